// Round 5
// baseline (283.756 us; speedup 1.0000x reference)
//
#include <hip/hip_runtime.h>
#include <hip/hip_bf16.h>
#include <math.h>

// Problem constants
#define Bc 8
#define Nc 512
#define Tc 64
#define Cc 128
#define Mc 32
#define MEMc 20
#define Ec 4

// LDS strides (bf16 elements)
#define LDK  40   // sh_k  [64][40]
#define LDVT 72   // sh_vt [32][72]
#define LDP  72   // sh_p  [64][72] (post-barrier), aliased with sh_p2 [64][40] (pre-barrier)
#define LDP2 40

#define GRID_BLOCKS 2048
#define UNITS_PER_BLOCK 8   // 16384 / 2048

typedef short bf16x8 __attribute__((ext_vector_type(8)));
typedef float f32x4  __attribute__((ext_vector_type(4)));

__device__ __forceinline__ unsigned short f2bfu(float f) {
    return __builtin_bit_cast(unsigned short, __float2bfloat16(f));
}
__device__ __forceinline__ unsigned pk2bf(float x, float y) {
    return ((unsigned)f2bfu(y) << 16) | (unsigned)f2bfu(x);
}

// ---- prep: wt[mat][e][m][c] bf16 (blocks 0..191); bankM[m][k] bf16 + G2[k][2] (block 192)
__global__ void prep(const float* __restrict__ Wq, const float* __restrict__ Wk,
                     const float* __restrict__ Wv, const float* __restrict__ membank,
                     const float* __restrict__ iq,
                     short* __restrict__ wt, short* __restrict__ bankM,
                     float* __restrict__ G2) {
    const int t = threadIdx.x;
    if (blockIdx.x < 192) {
        int idx = blockIdx.x * 256 + t;                 // 49152 = 3*4*32*128
        int c = idx & 127, m = (idx >> 7) & 31, e = (idx >> 12) & 3, mat = idx >> 14;
        const float* W = (mat == 0) ? Wq : (mat == 1) ? Wk : Wv;
        wt[idx] = (short)f2bfu(W[((size_t)e * Cc + c) * Mc + m]);
    } else {
        for (int idx = t; idx < Mc * 32; idx += 256) {
            int m = idx >> 5, k = idx & 31;
            bankM[idx] = (short)f2bfu((k < MEMc) ? membank[k * Mc + m] : 0.f);
        }
        if (t < MEMc) {
            float g0 = 0.f, g1 = 0.f;
            for (int m = 0; m < Mc; ++m) {
                float b = membank[t * Mc + m];
                g0 = fmaf(iq[m], b, g0);
                g1 = fmaf(iq[Mc + m], b, g1);
            }
            G2[2 * t]     = g0;
            G2[2 * t + 1] = g1;
        }
    }
}

__global__ __launch_bounds__(256, 8) void mg_mfma(
    const float* __restrict__ input,    // [B,N,T,2]
    const float* __restrict__ hidden,   // [E,B,N,T,C]
    const short* __restrict__ wt,       // [3][E][32][128] bf16
    const short* __restrict__ bankM,    // [32][32] bf16 (memory^T, K zero-padded)
    const float* __restrict__ G2,       // [20][2] fp32
    float* __restrict__ out)            // [B,N,T,1,E]
{
    __shared__ short sh_k [Tc * LDK];    // 5120 B
    __shared__ short sh_vt[Mc * LDVT];   // 4608 B
    __shared__ short sh_pu[Tc * LDP];    // 9216 B : P2 pre-barrier, P post-barrier
                                         // total 18944 B -> 8 blocks/CU

    const int t    = threadIdx.x;
    const int w    = t >> 6;
    const int lane = t & 63;
    const int lo   = lane & 15;
    const int hi   = lane >> 4;

    // iteration-major over experts: all resident blocks share one expert's weights
    for (int it = 0; it < UNITS_PER_BLOCK; ++it) {
        const int unit = it * GRID_BLOCKS + blockIdx.x;
        const int bn   = unit & 4095;
        const int e    = unit >> 12;

        // ---- A: issue hidden + input loads BEFORE the LDS-reuse barrier
        float4 h4[8];
        {
            const float* hrow = hidden + (((size_t)(e * 4096 + bn)) * Tc + w * 16 + lo) * Cc + hi * 8;
            #pragma unroll
            for (int kt = 0; kt < 4; ++kt) {
                h4[2 * kt]     = *(const float4*)(hrow + kt * 32);
                h4[2 * kt + 1] = *(const float4*)(hrow + kt * 32 + 4);
            }
        }
        const float2 in2 = *(const float2*)(input + ((size_t)bn * Tc + lane) * 2);

        __syncthreads();   // LDS of previous iteration fully consumed before overwrite

        // ---- B: mem-gate, row = lane, UNNORMALIZED exp (1/l cancels in cosine;
        //         logits = input@G are O(0.1), no max-subtraction needed)
        {
            unsigned pd[10];
            #pragma unroll
            for (int kp = 0; kp < 10; ++kp) {
                const float4 g = *(const float4*)(G2 + 4 * kp);   // slots 2kp, 2kp+1
                const float s0 = in2.x * g.x + in2.y * g.y;
                const float s1 = in2.x * g.z + in2.y * g.w;
                pd[kp] = pk2bf(__expf(s0), __expf(s1));
            }
            if ((lane >> 4) == w) {           // wave w owns rows [16w,16w+16): lane==row
                uint4* dst = (uint4*)&sh_pu[lane * LDP2];
                dst[0] = (uint4){pd[0], pd[1], pd[2], pd[3]};
                dst[1] = (uint4){pd[4], pd[5], pd[6], pd[7]};
                dst[2] = (uint4){pd[8], pd[9], 0u, 0u};
                dst[3] = (uint4){0u, 0u, 0u, 0u};
            }
        }

        // ---- C: transposed projections  qT/kT/vT = W^T @ H^T
        bf16x8 a[4];
        #pragma unroll
        for (int kt = 0; kt < 4; ++kt) {
            const float4 x = h4[2 * kt], y = h4[2 * kt + 1];
            uint4 u = (uint4){pk2bf(x.x, x.y), pk2bf(x.z, x.w), pk2bf(y.x, y.y), pk2bf(y.z, y.w)};
            a[kt] = __builtin_bit_cast(bf16x8, u);
        }
        f32x4 q_[2], k_[2], v_[2];
        #pragma unroll
        for (int nt = 0; nt < 2; ++nt) {
            q_[nt] = (f32x4){0.f, 0.f, 0.f, 0.f};
            k_[nt] = (f32x4){0.f, 0.f, 0.f, 0.f};
            v_[nt] = (f32x4){0.f, 0.f, 0.f, 0.f};
        }
        {
            const short* wb = wt + (((size_t)e * Mc) + lo) * Cc + hi * 8;
            #pragma unroll
            for (int nt = 0; nt < 2; ++nt) {
                const short* p0 = wb + nt * 16 * Cc;
                #pragma unroll
                for (int kt = 0; kt < 4; ++kt) {
                    const bf16x8 aq = *(const bf16x8*)(p0 + kt * 32);
                    const bf16x8 ak = *(const bf16x8*)(p0 + 4 * Mc * Cc + kt * 32);
                    const bf16x8 av = *(const bf16x8*)(p0 + 8 * Mc * Cc + kt * 32);
                    q_[nt] = __builtin_amdgcn_mfma_f32_16x16x32_bf16(aq, a[kt], q_[nt], 0, 0, 0);
                    k_[nt] = __builtin_amdgcn_mfma_f32_16x16x32_bf16(ak, a[kt], k_[nt], 0, 0, 0);
                    v_[nt] = __builtin_amdgcn_mfma_f32_16x16x32_bf16(av, a[kt], v_[nt], 0, 0, 0);
                }
            }
        }
        // K -> LDS row-major [s][m]; V -> LDS as V^T [m][s]
        unsigned q_pk[4];
        #pragma unroll
        for (int nt = 0; nt < 2; ++nt) {
            uint2 kw = (uint2){pk2bf(k_[nt][0], k_[nt][1]), pk2bf(k_[nt][2], k_[nt][3])};
            *(uint2*)&sh_k[(w * 16 + lo) * LDK + nt * 16 + hi * 4] = kw;
            #pragma unroll
            for (int j = 0; j < 4; ++j)
                sh_vt[(nt * 16 + hi * 4 + j) * LDVT + w * 16 + lo] = (short)f2bfu(v_[nt][j]);
            q_pk[nt * 2]     = pk2bf(q_[nt][0], q_[nt][1]);
            q_pk[nt * 2 + 1] = pk2bf(q_[nt][2], q_[nt][3]);
        }

        // ---- D: memories^T = bank^T @ P2^T (own wave's P2 rows, pre-barrier)
        f32x4 am[2];
        am[0] = (f32x4){0.f, 0.f, 0.f, 0.f};
        am[1] = (f32x4){0.f, 0.f, 0.f, 0.f};
        {
            const bf16x8 bp2 = *(const bf16x8*)&sh_pu[(w * 16 + lo) * LDP2 + hi * 8];
            #pragma unroll
            for (int nt = 0; nt < 2; ++nt) {
                const bf16x8 ab = *(const bf16x8*)(bankM + (nt * 16 + lo) * 32 + hi * 8);
                am[nt] = __builtin_amdgcn_mfma_f32_16x16x32_bf16(ab, bp2, am[nt], 0, 0, 0);
            }
        }

        __syncthreads();   // sh_k/sh_vt complete; sh_pu P2 consumed

        // ---- E: energy^T = K @ Q^T. Q B-frag via ds_bpermute from q_pk.
        {
            const int A01 = (((hi & 1) * 32) + lo) << 2;
            const int A23 = A01 + 64;
            unsigned qb0, qb1, qb2, qb3;
            {
                unsigned l0 = __builtin_amdgcn_ds_bpermute(A01, (int)q_pk[0]);
                unsigned h0 = __builtin_amdgcn_ds_bpermute(A01, (int)q_pk[2]);
                unsigned l1 = __builtin_amdgcn_ds_bpermute(A01, (int)q_pk[1]);
                unsigned h1 = __builtin_amdgcn_ds_bpermute(A01, (int)q_pk[3]);
                unsigned l2 = __builtin_amdgcn_ds_bpermute(A23, (int)q_pk[0]);
                unsigned h2 = __builtin_amdgcn_ds_bpermute(A23, (int)q_pk[2]);
                unsigned l3 = __builtin_amdgcn_ds_bpermute(A23, (int)q_pk[1]);
                unsigned h3 = __builtin_amdgcn_ds_bpermute(A23, (int)q_pk[3]);
                qb0 = (hi < 2) ? l0 : h0;
                qb1 = (hi < 2) ? l1 : h1;
                qb2 = (hi < 2) ? l2 : h2;
                qb3 = (hi < 2) ? l3 : h3;
            }
            const bf16x8 bq = __builtin_bit_cast(bf16x8, (uint4){qb0, qb1, qb2, qb3});

            f32x4 en[4];
            #pragma unroll
            for (int st = 0; st < 4; ++st) {
                const bf16x8 akf = *(const bf16x8*)&sh_k[(st * 16 + lo) * LDK + hi * 8];
                en[st] = __builtin_amdgcn_mfma_f32_16x16x32_bf16(
                    akf, bq, (f32x4){0.f, 0.f, 0.f, 0.f}, 0, 0, 0);
            }
            float mx = -1e30f;
            #pragma unroll
            for (int st = 0; st < 4; ++st)
                #pragma unroll
                for (int j = 0; j < 4; ++j) mx = fmaxf(mx, en[st][j]);
            mx = fmaxf(mx, __shfl_xor(mx, 16));
            mx = fmaxf(mx, __shfl_xor(mx, 32));
            #pragma unroll
            for (int st = 0; st < 4; ++st) {
                uint2 pw = (uint2){pk2bf(__expf(en[st][0] - mx), __expf(en[st][1] - mx)),
                                   pk2bf(__expf(en[st][2] - mx), __expf(en[st][3] - mx))};
                *(uint2*)&sh_pu[(w * 16 + lo) * LDP + st * 16 + hi * 4] = pw;
            }
        }

        // ---- F: att^T = V^T @ P^T ; cosine vs in-register memories^T
        f32x4 av[2];
        av[0] = (f32x4){0.f, 0.f, 0.f, 0.f};
        av[1] = (f32x4){0.f, 0.f, 0.f, 0.f};
        {
            bf16x8 bp[2];
            #pragma unroll
            for (int kt = 0; kt < 2; ++kt)
                bp[kt] = *(const bf16x8*)&sh_pu[(w * 16 + lo) * LDP + kt * 32 + hi * 8];
            #pragma unroll
            for (int nt = 0; nt < 2; ++nt)
                #pragma unroll
                for (int kt = 0; kt < 2; ++kt) {
                    const bf16x8 avt = *(const bf16x8*)&sh_vt[(nt * 16 + lo) * LDVT + kt * 32 + hi * 8];
                    av[nt] = __builtin_amdgcn_mfma_f32_16x16x32_bf16(avt, bp[kt], av[nt], 0, 0, 0);
                }
        }
        {
            float d = 0.f, na = 0.f, nb = 0.f;
            #pragma unroll
            for (int nt = 0; nt < 2; ++nt)
                #pragma unroll
                for (int j = 0; j < 4; ++j) {
                    const float av_ = av[nt][j], am_ = am[nt][j];
                    d  = fmaf(av_, am_, d);
                    na = fmaf(av_, av_, na);
                    nb = fmaf(am_, am_, nb);
                }
            d  += __shfl_xor(d, 16);  d  += __shfl_xor(d, 32);
            na += __shfl_xor(na, 16); na += __shfl_xor(na, 32);
            nb += __shfl_xor(nb, 16); nb += __shfl_xor(nb, 32);
            if (hi == 0) {
                const float denom = fmaxf(sqrtf(na), 1e-8f) * fmaxf(sqrtf(nb), 1e-8f);
                out[((size_t)bn * Tc + w * 16 + lo) * Ec + e] = d / denom;
            }
        }
    }
}

extern "C" void kernel_launch(void* const* d_in, const int* in_sizes, int n_in,
                              void* d_out, int out_size, void* d_ws, size_t ws_size,
                              hipStream_t stream) {
    const float* input   = (const float*)d_in[0];
    const float* hidden  = (const float*)d_in[1];
    const float* membank = (const float*)d_in[2];
    const float* iq      = (const float*)d_in[3];
    const float* Wq      = (const float*)d_in[4];
    const float* Wk      = (const float*)d_in[5];
    const float* Wv      = (const float*)d_in[6];
    float* out = (float*)d_out;

    short* wt    = (short*)d_ws;                       // 98304 B
    short* bankM = (short*)((char*)d_ws + 98304);      //  2048 B
    float* G2    = (float*)((char*)d_ws + 100352);     //   160 B

    prep<<<193, 256, 0, stream>>>(Wq, Wk, Wv, membank, iq, wt, bankM, G2);
    mg_mfma<<<GRID_BLOCKS, 256, 0, stream>>>(input, hidden, wt, bankM, G2, out);
}